// Round 5
// baseline (278.438 us; speedup 1.0000x reference)
//
#include <hip/hip_runtime.h>
#include <stdint.h>

#define D_MODEL 768
#define BATCH   16
#define SEQ     2048
#define M_ROWS  (BATCH * SEQ)   // 32768
#define LN_EPS  1e-5f

#define CHUNKS  64
#define CLEN    (SEQ / CHUNKS)  // 32
#define PFA     4               // prefetch depth, scan phases 1/3
#define PFB     8               // prefetch depth, phase 2

typedef __attribute__((ext_vector_type(4))) float  f32x4;
typedef __attribute__((ext_vector_type(8))) __bf16 bf16x8;

__device__ __forceinline__ unsigned short f2bf(float f) {
    union { float f; uint32_t u; } v; v.f = f;
    uint32_t u = v.u;
    uint32_t r = (u + 0x7FFFu + ((u >> 16) & 1u)) >> 16;   // RNE
    return (unsigned short)r;
}
__device__ __forceinline__ float bf2f(unsigned short u) {
    union { uint32_t u; float f; } v; v.u = (uint32_t)u << 16; return v.f;
}

__device__ __forceinline__ void gload_lds16(const void* g, void* l) {
    __builtin_amdgcn_global_load_lds(
        (const __attribute__((address_space(1))) unsigned int*)g,
        (__attribute__((address_space(3))) unsigned int*)l,
        16, 0, 0);
}

// ---------------- Kernel 1: convert x -> bf16, fused decay GEMV ----------------
__global__ __launch_bounds__(256) void k_conv_decay(
    const float* __restrict__ x, const float* __restrict__ Wd,
    const float* __restrict__ bd, unsigned short* __restrict__ xb,
    float* __restrict__ decay)
{
    int row = blockIdx.x;
    int i   = threadIdx.x;
    const float* xr = x + (size_t)row * D_MODEL;
    float v0 = xr[i], v1 = xr[i + 256], v2 = xr[i + 512];
    unsigned short* xbr = xb + (size_t)row * D_MODEL;
    xbr[i] = f2bf(v0); xbr[i + 256] = f2bf(v1); xbr[i + 512] = f2bf(v2);

    float part = v0 * Wd[i] + v1 * Wd[i + 256] + v2 * Wd[i + 512];
    #pragma unroll
    for (int off = 32; off; off >>= 1) part += __shfl_down(part, off);
    __shared__ float wsum[4];
    int wid = i >> 6, lane = i & 63;
    if (lane == 0) wsum[wid] = part;
    __syncthreads();
    if (i == 0) {
        float s = wsum[0] + wsum[1] + wsum[2] + wsum[3] + bd[0];
        decay[row] = 1.f / (1.f + __expf(-s));
    }
}

// ---------------- Kernel 2: convert both weight matrices to bf16 (contiguous dest) ----------------
__global__ __launch_bounds__(256) void k_conv_w(
    const float* __restrict__ Wb, const float* __restrict__ Wi,
    unsigned short* __restrict__ Wdst)   // (1536,768): rows 0..767 = W_biv, 768..1535 = W_in
{
    const int NW = D_MODEL * D_MODEL;          // 589824
    int g = blockIdx.x * 256 + threadIdx.x;
    int base = g * 4;
    unsigned short* dst = Wdst + base;
    const float* src;
    if (base < NW) { src = Wb + base; }
    else           { src = Wi + (base - NW); }
    float4 v = *(const float4*)src;
    ushort4 o;
    o.x = f2bf(v.x); o.y = f2bf(v.y); o.z = f2bf(v.z); o.w = f2bf(v.w);
    *(ushort4*)dst = o;
}

// ---------------- Kernel 3: fused bf16 MFMA GEMM, double-buffered 2-phase ----------------
#define BM 128
#define BN 128
#define NBX 12   // 1536/BN

__global__ __launch_bounds__(256) void k_gemm_fused(
    const unsigned short* __restrict__ A,    // (M,768) bf16
    const unsigned short* __restrict__ Bw,   // (1536,768) bf16
    const float* __restrict__ bias_biv, const float* __restrict__ bias_in,
    unsigned short* __restrict__ bivb, unsigned short* __restrict__ injb)
{
    const int K = D_MODEL;
    __shared__ unsigned short As0[BM * 32], Bs0[BN * 32];   // 16 KiB
    __shared__ unsigned short As1[BM * 32], Bs1[BN * 32];   // 16 KiB

    // XCD-chunked swizzle: 3072 blocks, 384 per XCD, contiguous tile ranges per XCD
    int id  = blockIdx.x;
    int swz = (id & 7) * (NBX * (M_ROWS / BM) / 8) + (id >> 3);
    int bxc = swz % NBX, byr = swz / NBX;
    int m0 = byr * BM, n0 = bxc * BN;

    int tid  = threadIdx.x;
    int wave = tid >> 6, lane = tid & 63;
    int wm = wave >> 1, wn = wave & 1;      // 2x2 wave grid, 64x64 per wave

    f32x4 acc[4][4] = {};

    auto STAGE = [&](unsigned short* As_, unsigned short* Bs_, int k0) {
        #pragma unroll
        for (int hh = 0; hh < 2; ++hh) {
            int c  = wave * 128 + hh * 64 + lane;
            int r  = c >> 2;
            int sl = (c & 3) ^ ((r >> 1) & 3);   // k-slot swizzle on GLOBAL side, LDS linear
            gload_lds16(A  + (size_t)(m0 + r) * K + k0 + sl * 8, (char*)As_ + c * 16);
            gload_lds16(Bw + (size_t)(n0 + r) * K + k0 + sl * 8, (char*)Bs_ + c * 16);
        }
    };
    auto COMPUTE = [&](const unsigned short* As_, const unsigned short* Bs_) {
        bf16x8 af[4], bfr[4];
        int kq = lane >> 4;          // k-slot 0..3
        int rl = lane & 15;
        #pragma unroll
        for (int i = 0; i < 4; ++i) {
            int ra = wm * 64 + i * 16 + rl;
            int ca = kq ^ ((ra >> 1) & 3);
            af[i]  = *reinterpret_cast<const bf16x8*>((const char*)As_ + ra * 64 + ca * 16);
            int rb = wn * 64 + i * 16 + rl;
            int cb = kq ^ ((rb >> 1) & 3);
            bfr[i] = *reinterpret_cast<const bf16x8*>((const char*)Bs_ + rb * 64 + cb * 16);
        }
        #pragma unroll
        for (int i = 0; i < 4; ++i)
            #pragma unroll
            for (int j = 0; j < 4; ++j)
                acc[i][j] = __builtin_amdgcn_mfma_f32_16x16x32_bf16(af[i], bfr[j], acc[i][j], 0, 0, 0);
    };

    STAGE(As0, Bs0, 0);
    __syncthreads();
    for (int k0 = 0; k0 < K; k0 += 64) {
        if (k0 + 32 < K) STAGE(As1, Bs1, k0 + 32);   // loads fly during MFMAs below
        COMPUTE(As0, Bs0);
        __syncthreads();                              // drains the in-flight stage
        if (k0 + 64 < K) STAGE(As0, Bs0, k0 + 64);
        COMPUTE(As1, Bs1);
        __syncthreads();
    }

    // epilogue: C/D layout col=lane&15, row=(lane>>4)*4+reg; convert to bf16
    unsigned short* Cout; const float* bias; int nloc;
    if (n0 < D_MODEL) { Cout = bivb; bias = bias_biv; nloc = n0; }
    else              { Cout = injb; bias = bias_in;  nloc = n0 - D_MODEL; }
    int cl = lane & 15;
    int rg = (lane >> 4) * 4;
    #pragma unroll
    for (int j = 0; j < 4; ++j) {
        int col = nloc + wn * 64 + j * 16 + cl;
        float bs = bias[col];
        #pragma unroll
        for (int i = 0; i < 4; ++i) {
            int rowb = m0 + wm * 64 + i * 16 + rg;
            #pragma unroll
            for (int r = 0; r < 4; ++r)
                Cout[(size_t)(rowb + r) * D_MODEL + col] = f2bf(acc[i][j][r] + bs);
        }
    }
}

// ---------------- Scan phase 1: per-(chain,chunk) operator compose only ----------------
__global__ __launch_bounds__(256) void k_scan_p1(
    const unsigned short* __restrict__ bivb, const unsigned short* __restrict__ injb,
    const float* __restrict__ decay,
    float* __restrict__ ops)          // per (b,c,j): {Qw,Qx,Qy,Qz,S,bx,by,bz}
{
    int j = threadIdx.x;
    int c = blockIdx.x & (CHUNKS - 1);
    int b = blockIdx.x >> 6;
    size_t rowbase = ((size_t)b * SEQ + c * CLEN) * D_MODEL + (size_t)j * 3;
    const unsigned short* bv = bivb + rowbase;
    const unsigned short* ij = injb + rowbase;
    const float* dk = decay + b * SEQ + c * CLEN;   // wave-uniform -> scalar loads

    float pbx[PFA], pby[PFA], pbz[PFA], pix[PFA], piy[PFA], piz[PFA], pd[PFA];
    #pragma unroll
    for (int p = 0; p < PFA; ++p) {
        size_t o = (size_t)p * D_MODEL;
        pbx[p] = bf2f(bv[o]); pby[p] = bf2f(bv[o + 1]); pbz[p] = bf2f(bv[o + 2]);
        pix[p] = bf2f(ij[o]); piy[p] = bf2f(ij[o + 1]); piz[p] = bf2f(ij[o + 2]);
        pd[p]  = dk[p];
    }

    float hx = 0.f, hy = 0.f, hz = 0.f;
    float Qw = 1.f, Qx = 0.f, Qy = 0.f, Qz = 0.f, S = 1.f;
    for (int t0 = 0; t0 < CLEN; t0 += PFA) {
        #pragma unroll
        for (int p = 0; p < PFA; ++p) {
            int t = t0 + p;
            float bx = pbx[p], by = pby[p], bz = pbz[p];
            float ix = pix[p], iy = piy[p], iz = piz[p];
            float d  = pd[p];
            int tn = t + PFA;
            if (tn < CLEN) {
                size_t o = (size_t)tn * D_MODEL;
                pbx[p] = bf2f(bv[o]); pby[p] = bf2f(bv[o + 1]); pbz[p] = bf2f(bv[o + 2]);
                pix[p] = bf2f(ij[o]); piy[p] = bf2f(ij[o + 1]); piz[p] = bf2f(ij[o + 2]);
                pd[p]  = dk[tn];
            }
            float n2   = bx * bx + by * by + bz * bz;
            float nrm  = fmaxf(__builtin_sqrtf(n2), 1e-8f);
            float half = 0.5f * nrm;
            float w = __cosf(half);
            float s = __sinf(half) / nrm;
            float qx = s * bz, qy = -s * by, qz = s * bx;   // reversed mapping
            float tx = 2.f * (qy * hz - qz * hy);
            float ty = 2.f * (qz * hx - qx * hz);
            float tz = 2.f * (qx * hy - qy * hx);
            float rx = hx + w * tx + (qy * tz - qz * ty);
            float ry = hy + w * ty + (qz * tx - qx * tz);
            float rz = hz + w * tz + (qx * ty - qy * tx);
            hx = fmaf(d, rx, ix);
            hy = fmaf(d, ry, iy);
            hz = fmaf(d, rz, iz);
            // compose total operator: Q <- q_step (x) Q ; S <- d*S
            float nQw = w * Qw - qx * Qx - qy * Qy - qz * Qz;
            float nQx = w * Qx + Qw * qx + (qy * Qz - qz * Qy);
            float nQy = w * Qy + Qw * qy + (qz * Qx - qx * Qz);
            float nQz = w * Qz + Qw * qz + (qx * Qy - qy * Qx);
            Qw = nQw; Qx = nQx; Qy = nQy; Qz = nQz;
            S *= d;
        }
    }
    float* op = ops + ((size_t)(b * CHUNKS + c) * 256 + j) * 8;
    f32x4 o0 = {Qw, Qx, Qy, Qz};
    f32x4 o1 = {S, hx, hy, hz};
    *(f32x4*)op = o0;
    *(f32x4*)(op + 4) = o1;
}

// ---------------- Scan phase 2: sequential fold of 64 chunk operators per chain ----------------
__global__ __launch_bounds__(64) void k_scan_p2(
    const float* __restrict__ ops, float* __restrict__ hs)
{
    int gid = blockIdx.x * 64 + threadIdx.x;   // 0..4095
    int j = gid & 255, b = gid >> 8;

    float q0[PFB], q1[PFB], q2[PFB], q3[PFB], sc[PFB], o0[PFB], o1[PFB], o2[PFB];
    #pragma unroll
    for (int p = 0; p < PFB; ++p) {
        const float* op = ops + ((size_t)(b * CHUNKS + p) * 256 + j) * 8;
        f32x4 a = *(const f32x4*)op, bb = *(const f32x4*)(op + 4);
        q0[p] = a[0]; q1[p] = a[1]; q2[p] = a[2]; q3[p] = a[3];
        sc[p] = bb[0]; o0[p] = bb[1]; o1[p] = bb[2]; o2[p] = bb[3];
    }
    float hx = 0.f, hy = 0.f, hz = 0.f;
    for (int c0 = 0; c0 < CHUNKS; c0 += PFB) {
        #pragma unroll
        for (int p = 0; p < PFB; ++p) {
            int c = c0 + p;
            float* h = hs + ((size_t)(b * CHUNKS + c) * 256 + j) * 3;
            h[0] = hx; h[1] = hy; h[2] = hz;     // h at entry of chunk c
            float w = q0[p], qx = q1[p], qy = q2[p], qz = q3[p];
            float s = sc[p], bx = o0[p], by = o1[p], bz = o2[p];
            int cn = c + PFB;
            if (cn < CHUNKS) {
                const float* op = ops + ((size_t)(b * CHUNKS + cn) * 256 + j) * 8;
                f32x4 a = *(const f32x4*)op, bb = *(const f32x4*)(op + 4);
                q0[p] = a[0]; q1[p] = a[1]; q2[p] = a[2]; q3[p] = a[3];
                sc[p] = bb[0]; o0[p] = bb[1]; o1[p] = bb[2]; o2[p] = bb[3];
            }
            float tx = 2.f * (qy * hz - qz * hy);
            float ty = 2.f * (qz * hx - qx * hz);
            float tz = 2.f * (qx * hy - qy * hx);
            float rx = hx + w * tx + (qy * tz - qz * ty);
            float ry = hy + w * ty + (qz * tx - qx * tz);
            float rz = hz + w * tz + (qx * ty - qy * tx);
            hx = fmaf(s, rx, bx);
            hy = fmaf(s, ry, by);
            hz = fmaf(s, rz, bz);
        }
    }
}

// ---------------- Scan phase 3: chunk scan + fused LayerNorm (4-step batched) + residual ----
__global__ __launch_bounds__(256) void k_scan_p3(
    const unsigned short* __restrict__ bivb, const unsigned short* __restrict__ injb,
    const float* __restrict__ decay, const float* __restrict__ hs,
    const float* __restrict__ x, const float* __restrict__ gamma,
    const float* __restrict__ beta, float* __restrict__ out)
{
    int blk = blockIdx.x;
    int c = blk & (CHUNKS - 1);
    int b = blk >> 6;
    int j = threadIdx.x;
    size_t rowbase = ((size_t)b * SEQ + c * CLEN) * D_MODEL + (size_t)j * 3;
    const unsigned short* bv = bivb + rowbase;
    const unsigned short* ij = injb + rowbase;
    const float*          xr = x    + rowbase;
    float*                po = out  + rowbase;
    const float* dk = decay + b * SEQ + c * CLEN;
    const float* h0 = hs + ((size_t)(b * CHUNKS + c) * 256 + j) * 3;
    float hx = h0[0], hy = h0[1], hz = h0[2];

    float g0 = gamma[j * 3], g1 = gamma[j * 3 + 1], g2 = gamma[j * 3 + 2];
    float e0 = beta[j * 3],  e1 = beta[j * 3 + 1],  e2 = beta[j * 3 + 2];

    float pbx[PFA], pby[PFA], pbz[PFA], pix[PFA], piy[PFA], piz[PFA], pd[PFA];
    float pxx[PFA], pxy[PFA], pxz[PFA];
    #pragma unroll
    for (int p = 0; p < PFA; ++p) {
        size_t o = (size_t)p * D_MODEL;
        pbx[p] = bf2f(bv[o]); pby[p] = bf2f(bv[o + 1]); pbz[p] = bf2f(bv[o + 2]);
        pix[p] = bf2f(ij[o]); piy[p] = bf2f(ij[o + 1]); piz[p] = bf2f(ij[o + 2]);
        pxx[p] = xr[o]; pxy[p] = xr[o + 1]; pxz[p] = xr[o + 2];
        pd[p]  = dk[p];
    }

    __shared__ float sbS[4][4], sbQ[4][4];   // [wave][p]
    __shared__ float mvm[4], mvr[4];
    int wid = j >> 6, lane = j & 63;

    for (int t0 = 0; t0 < CLEN; t0 += 4) {
        float hq[4][3], rxs[4][3];
        #pragma unroll
        for (int p = 0; p < 4; ++p) {
            int t = t0 + p;
            float bx = pbx[p], by = pby[p], bz = pbz[p];
            float ix = pix[p], iy = piy[p], iz = piz[p];
            rxs[p][0] = pxx[p]; rxs[p][1] = pxy[p]; rxs[p][2] = pxz[p];
            float d  = pd[p];
            int tn = t + 4;
            if (tn < CLEN) {
                size_t o = (size_t)tn * D_MODEL;
                pbx[p] = bf2f(bv[o]); pby[p] = bf2f(bv[o + 1]); pbz[p] = bf2f(bv[o + 2]);
                pix[p] = bf2f(ij[o]); piy[p] = bf2f(ij[o + 1]); piz[p] = bf2f(ij[o + 2]);
                pxx[p] = xr[o]; pxy[p] = xr[o + 1]; pxz[p] = xr[o + 2];
                pd[p]  = dk[tn];
            }
            float n2   = bx * bx + by * by + bz * bz;
            float nrm  = fmaxf(__builtin_sqrtf(n2), 1e-8f);
            float half = 0.5f * nrm;
            float w = __cosf(half);
            float s = __sinf(half) / nrm;
            float qx = s * bz, qy = -s * by, qz = s * bx;
            float tx = 2.f * (qy * hz - qz * hy);
            float ty = 2.f * (qz * hx - qx * hz);
            float tz = 2.f * (qx * hy - qy * hx);
            float rx = hx + w * tx + (qy * tz - qz * ty);
            float ry = hy + w * ty + (qz * tx - qx * tz);
            float rz = hz + w * tz + (qx * ty - qy * tx);
            hx = fmaf(d, rx, ix);
            hy = fmaf(d, ry, iy);
            hz = fmaf(d, rz, iz);
            hq[p][0] = hx; hq[p][1] = hy; hq[p][2] = hz;
        }
        // batched LN reduce for 4 timesteps (8 chains, ILP-overlapped)
        float ss[4], qq[4];
        #pragma unroll
        for (int p = 0; p < 4; ++p) {
            ss[p] = hq[p][0] + hq[p][1] + hq[p][2];
            qq[p] = hq[p][0] * hq[p][0] + hq[p][1] * hq[p][1] + hq[p][2] * hq[p][2];
        }
        #pragma unroll
        for (int off = 32; off; off >>= 1) {
            #pragma unroll
            for (int p = 0; p < 4; ++p) {
                ss[p] += __shfl_down(ss[p], off);
                qq[p] += __shfl_down(qq[p], off);
            }
        }
        if (lane == 0) {
            #pragma unroll
            for (int p = 0; p < 4; ++p) { sbS[wid][p] = ss[p]; sbQ[wid][p] = qq[p]; }
        }
        __syncthreads();
        if (j < 4) {
            float S = sbS[0][j] + sbS[1][j] + sbS[2][j] + sbS[3][j];
            float Q = sbQ[0][j] + sbQ[1][j] + sbQ[2][j] + sbQ[3][j];
            float mean = S * (1.f / 768.f);
            float var  = Q * (1.f / 768.f) - mean * mean;
            mvm[j] = mean; mvr[j] = rsqrtf(var + LN_EPS);
        }
        __syncthreads();
        #pragma unroll
        for (int p = 0; p < 4; ++p) {
            float mean = mvm[p], rstd = mvr[p];
            float* o2 = po + (size_t)(t0 + p) * D_MODEL;
            o2[0] = (hq[p][0] - mean) * rstd * g0 + e0 + rxs[p][0];
            o2[1] = (hq[p][1] - mean) * rstd * g1 + e1 + rxs[p][1];
            o2[2] = (hq[p][2] - mean) * rstd * g2 + e2 + rxs[p][2];
        }
    }
}

extern "C" void kernel_launch(void* const* d_in, const int* in_sizes, int n_in,
                              void* d_out, int out_size, void* d_ws, size_t ws_size,
                              hipStream_t stream) {
    const float* x     = (const float*)d_in[0];
    const float* W_biv = (const float*)d_in[1];
    const float* b_biv = (const float*)d_in[2];
    const float* W_dec = (const float*)d_in[3];
    const float* b_dec = (const float*)d_in[4];
    const float* W_in  = (const float*)d_in[5];
    const float* b_in  = (const float*)d_in[6];
    const float* gamma = (const float*)d_in[7];
    const float* beta  = (const float*)d_in[8];
    float* out = (float*)d_out;

    // workspace layout (153.5 MB)
    char* ws = (char*)d_ws;
    unsigned short* xb    = (unsigned short*)(ws);               // 50,331,648 B (dead after GEMM)
    unsigned short* Wcat  = (unsigned short*)(ws + 50331648);    //  2,359,296 B (1536x768 bf16)
    float*          decay = (float*)         (ws + 52690944);    //    131,072 B
    unsigned short* bivb  = (unsigned short*)(ws + 52822016);    // 50,331,648 B (bf16)
    unsigned short* injb  = (unsigned short*)(ws + 103153664);   // 50,331,648 B (bf16)
    // scan scratch reuses the xb region (dead after GEMM)
    float*          ops   = (float*)(ws);                        //  8,388,608 B
    float*          hs    = (float*)(ws + 8388608);              //  3,145,728 B

    (void)in_sizes; (void)n_in; (void)out_size; (void)ws_size;

    k_conv_decay<<<M_ROWS, 256, 0, stream>>>(x, W_dec, b_dec, xb, decay);
    k_conv_w    <<<1152,   256, 0, stream>>>(W_biv, W_in, Wcat);
    k_gemm_fused<<<NBX * (M_ROWS / BM), 256, 0, stream>>>(xb, Wcat, b_biv, b_in, bivb, injb);
    k_scan_p1   <<<1024, 256, 0, stream>>>(bivb, injb, decay, ops);
    k_scan_p2   <<<64,   64,  0, stream>>>(ops, hs);
    k_scan_p3   <<<1024, 256, 0, stream>>>(bivb, injb, decay, hs, x, gamma, beta, out);
}

// Round 6
// 232.499 us; speedup vs baseline: 1.1976x; 1.1976x over previous
//
#include <hip/hip_runtime.h>
#include <stdint.h>

#define D_MODEL 768
#define BATCH   16
#define SEQ     2048
#define M_ROWS  (BATCH * SEQ)   // 32768
#define LN_EPS  1e-5f

#define CHUNKS  64
#define CLEN    (SEQ / CHUNKS)  // 32
#define PFB     8               // prefetch depth, phase 2

typedef __attribute__((ext_vector_type(4))) float        f32x4;
typedef __attribute__((ext_vector_type(8))) __bf16       bf16x8;
typedef __attribute__((ext_vector_type(2))) unsigned int u32x2;

__device__ __forceinline__ unsigned short f2bf(float f) {
    union { float f; uint32_t u; } v; v.f = f;
    uint32_t u = v.u;
    uint32_t r = (u + 0x7FFFu + ((u >> 16) & 1u)) >> 16;   // RNE
    return (unsigned short)r;
}
__device__ __forceinline__ float bf2f(unsigned short u) {
    union { uint32_t u; float f; } v; v.u = (uint32_t)u << 16; return v.f;
}
// extract element k (0..3) of a packed quad (4 bf16 in 8B)
__device__ __forceinline__ float bfx(u32x2 v, int k) {
    unsigned int w = (k & 2) ? v[1] : v[0];
    return bf2f((unsigned short)(w >> ((k & 1) * 16)));
}

__device__ __forceinline__ void gload_lds16(const void* g, void* l) {
    __builtin_amdgcn_global_load_lds(
        (const __attribute__((address_space(1))) unsigned int*)g,
        (__attribute__((address_space(3))) unsigned int*)l,
        16, 0, 0);
}

// ---------------- Kernel 1: convert x -> bf16, fused decay GEMV ----------------
__global__ __launch_bounds__(256) void k_conv_decay(
    const float* __restrict__ x, const float* __restrict__ Wd,
    const float* __restrict__ bd, unsigned short* __restrict__ xb,
    float* __restrict__ decay)
{
    int row = blockIdx.x;
    int i   = threadIdx.x;
    const float* xr = x + (size_t)row * D_MODEL;
    float v0 = xr[i], v1 = xr[i + 256], v2 = xr[i + 512];
    unsigned short* xbr = xb + (size_t)row * D_MODEL;
    xbr[i] = f2bf(v0); xbr[i + 256] = f2bf(v1); xbr[i + 512] = f2bf(v2);

    float part = v0 * Wd[i] + v1 * Wd[i + 256] + v2 * Wd[i + 512];
    #pragma unroll
    for (int off = 32; off; off >>= 1) part += __shfl_down(part, off);
    __shared__ float wsum[4];
    int wid = i >> 6, lane = i & 63;
    if (lane == 0) wsum[wid] = part;
    __syncthreads();
    if (i == 0) {
        float s = wsum[0] + wsum[1] + wsum[2] + wsum[3] + bd[0];
        decay[row] = 1.f / (1.f + __expf(-s));
    }
}

// ---------------- Kernel 2: convert both weight matrices to bf16 (contiguous dest) ----------------
__global__ __launch_bounds__(256) void k_conv_w(
    const float* __restrict__ Wb, const float* __restrict__ Wi,
    unsigned short* __restrict__ Wdst)   // (1536,768): rows 0..767 = W_biv, 768..1535 = W_in
{
    const int NW = D_MODEL * D_MODEL;          // 589824
    int g = blockIdx.x * 256 + threadIdx.x;
    int base = g * 4;
    unsigned short* dst = Wdst + base;
    const float* src;
    if (base < NW) { src = Wb + base; }
    else           { src = Wi + (base - NW); }
    float4 v = *(const float4*)src;
    ushort4 o;
    o.x = f2bf(v.x); o.y = f2bf(v.y); o.z = f2bf(v.z); o.w = f2bf(v.w);
    *(ushort4*)dst = o;
}

// ---------------- Kernel 3: fused bf16 MFMA GEMM, C(M,1536) = A * W^T + bias ----------------
// Output in QUAD-PACKED layout: Cq[(row>>2)*768 + col] = u32x2 of 4 bf16 (rows row..row+3).
#define BM 128
#define BN 128
#define NBX 12   // 1536/BN

__global__ __launch_bounds__(256) void k_gemm_fused(
    const unsigned short* __restrict__ A,    // (M,768) bf16 row-major
    const unsigned short* __restrict__ Bw,   // (1536,768) bf16 row-major
    const float* __restrict__ bias_biv, const float* __restrict__ bias_in,
    u32x2* __restrict__ bivq, u32x2* __restrict__ injq)
{
    const int K = D_MODEL;
    __shared__ unsigned short As[BM * 32];  // 8 KiB
    __shared__ unsigned short Bs[BN * 32];  // 8 KiB

    // XCD-chunked swizzle: 3072 blocks, 384 per XCD, contiguous tile ranges per XCD
    int id  = blockIdx.x;
    int swz = (id & 7) * (NBX * (M_ROWS / BM) / 8) + (id >> 3);
    int bxc = swz % NBX, byr = swz / NBX;
    int m0 = byr * BM, n0 = bxc * BN;

    int tid  = threadIdx.x;
    int wave = tid >> 6, lane = tid & 63;
    int wm = wave >> 1, wn = wave & 1;      // 2x2 wave grid, 64x64 per wave

    f32x4 acc[4][4] = {};

    for (int k0 = 0; k0 < K; k0 += 32) {
        // stage A,B tiles; k-slot XOR-swizzled on the GLOBAL side (LDS dest linear)
        #pragma unroll
        for (int hh = 0; hh < 2; ++hh) {
            int c  = wave * 128 + hh * 64 + lane;
            int r  = c >> 2;
            int sl = (c & 3) ^ ((r >> 1) & 3);
            gload_lds16(A  + (size_t)(m0 + r) * K + k0 + sl * 8, (char*)As + c * 16);
            gload_lds16(Bw + (size_t)(n0 + r) * K + k0 + sl * 8, (char*)Bs + c * 16);
        }
        __syncthreads();

        bf16x8 af[4], bfr[4];
        int kq = lane >> 4;          // k-slot 0..3
        int rl = lane & 15;
        #pragma unroll
        for (int i = 0; i < 4; ++i) {
            int ra = wm * 64 + i * 16 + rl;
            int ca = kq ^ ((ra >> 1) & 3);
            af[i]  = *reinterpret_cast<const bf16x8*>((const char*)As + ra * 64 + ca * 16);
            int rb = wn * 64 + i * 16 + rl;
            int cb = kq ^ ((rb >> 1) & 3);
            bfr[i] = *reinterpret_cast<const bf16x8*>((const char*)Bs + rb * 64 + cb * 16);
        }
        #pragma unroll
        for (int i = 0; i < 4; ++i)
            #pragma unroll
            for (int j = 0; j < 4; ++j)
                acc[i][j] = __builtin_amdgcn_mfma_f32_16x16x32_bf16(af[i], bfr[j], acc[i][j], 0, 0, 0);
        __syncthreads();
    }

    // epilogue: pack the 4 acc rows (quad-aligned) into one 8B store per (i,j)
    u32x2* Cq; const float* bias; int nloc;
    if (n0 < D_MODEL) { Cq = bivq; bias = bias_biv; nloc = n0; }
    else              { Cq = injq; bias = bias_in;  nloc = n0 - D_MODEL; }
    int cl = lane & 15;
    int q4 = lane >> 4;
    int rowq0 = (m0 + wm * 64) >> 2;   // quad-row base for this wave
    #pragma unroll
    for (int j = 0; j < 4; ++j) {
        int col = nloc + wn * 64 + j * 16 + cl;
        float bs = bias[col];
        #pragma unroll
        for (int i = 0; i < 4; ++i) {
            f32x4 a = acc[i][j];
            unsigned int lo = (unsigned int)f2bf(a[0] + bs) | ((unsigned int)f2bf(a[1] + bs) << 16);
            unsigned int hi = (unsigned int)f2bf(a[2] + bs) | ((unsigned int)f2bf(a[3] + bs) << 16);
            size_t qi = (size_t)(rowq0 + i * 4 + q4) * D_MODEL + col;
            u32x2 pk = {lo, hi};
            Cq[qi] = pk;
        }
    }
}

// ---------------- Scan step macros ----------------
#define QSTEP_CORE(BX,BY,BZ, IX,IY,IZ, DD)                              \
    {   float n2   = (BX)*(BX) + (BY)*(BY) + (BZ)*(BZ);                 \
        float nrm  = fmaxf(__builtin_sqrtf(n2), 1e-8f);                 \
        float half = 0.5f * nrm;                                        \
        float w = __cosf(half);                                         \
        float s = __sinf(half) / nrm;                                   \
        float qx = s * (BZ), qy = -s * (BY), qz = s * (BX);             \
        float tx = 2.f * (qy * hz - qz * hy);                           \
        float ty = 2.f * (qz * hx - qx * hz);                           \
        float tz = 2.f * (qx * hy - qy * hx);                           \
        float rx = hx + w * tx + (qy * tz - qz * ty);                   \
        float ry = hy + w * ty + (qz * tx - qx * tz);                   \
        float rz = hz + w * tz + (qx * ty - qy * tx);                   \
        hx = fmaf((DD), rx, (IX));                                      \
        hy = fmaf((DD), ry, (IY));                                      \
        hz = fmaf((DD), rz, (IZ));                                      \
        float nQw = w * Qw - qx * Qx - qy * Qy - qz * Qz;               \
        float nQx = w * Qx + Qw * qx + (qy * Qz - qz * Qy);             \
        float nQy = w * Qy + Qw * qy + (qz * Qx - qx * Qz);             \
        float nQz = w * Qz + Qw * qz + (qx * Qy - qy * Qx);             \
        Qw = nQw; Qx = nQx; Qy = nQy; Qz = nQz;                         \
        S *= (DD);                                                      \
    }

// ---------------- Scan phase 1: per-(chain,chunk) operator compose (quad-packed reads) ----
__global__ __launch_bounds__(256) void k_scan_p1(
    const u32x2* __restrict__ bivq, const u32x2* __restrict__ injq,
    const float* __restrict__ decay,
    float* __restrict__ ops)          // per (b,c,j): {Qw,Qx,Qy,Qz,S,bx,by,bz}
{
    int j = threadIdx.x;
    int c = blockIdx.x & (CHUNKS - 1);
    int b = blockIdx.x >> 6;
    size_t qrow = ((size_t)b * SEQ + (size_t)c * CLEN) >> 2;
    const u32x2* bv = bivq + qrow * D_MODEL + 3 * j;
    const u32x2* ij = injq + qrow * D_MODEL + 3 * j;
    const float* dk = decay + (size_t)b * SEQ + c * CLEN;

    u32x2 Ab0, Ab1, Ab2, Ai0, Ai1, Ai2; f32x4 Ad;
    u32x2 Bb0, Bb1, Bb2, Bi0, Bi1, Bi2; f32x4 Bd;

    #define LOADQ1(P, q)                                                  \
        P##b0 = bv[(size_t)(q) * D_MODEL + 0];                            \
        P##b1 = bv[(size_t)(q) * D_MODEL + 1];                            \
        P##b2 = bv[(size_t)(q) * D_MODEL + 2];                            \
        P##i0 = ij[(size_t)(q) * D_MODEL + 0];                            \
        P##i1 = ij[(size_t)(q) * D_MODEL + 1];                            \
        P##i2 = ij[(size_t)(q) * D_MODEL + 2];                            \
        P##d  = *(const f32x4*)(dk + (q) * 4);

    #define PROC41(P)                                                     \
        _Pragma("unroll")                                                 \
        for (int k = 0; k < 4; ++k) {                                     \
            float bx = bfx(P##b0, k), by = bfx(P##b1, k), bz = bfx(P##b2, k); \
            float ix = bfx(P##i0, k), iy = bfx(P##i1, k), iz = bfx(P##i2, k); \
            float d = P##d[k];                                            \
            QSTEP_CORE(bx, by, bz, ix, iy, iz, d)                         \
        }

    float hx = 0.f, hy = 0.f, hz = 0.f;
    float Qw = 1.f, Qx = 0.f, Qy = 0.f, Qz = 0.f, S = 1.f;

    LOADQ1(A, 0)
    LOADQ1(B, 1)
    #pragma unroll
    for (int q0 = 0; q0 < CLEN / 4; q0 += 2) {
        PROC41(A)
        if (q0 + 2 < CLEN / 4) { LOADQ1(A, q0 + 2) }
        PROC41(B)
        if (q0 + 3 < CLEN / 4) { LOADQ1(B, q0 + 3) }
    }
    #undef LOADQ1
    #undef PROC41

    float* op = ops + ((size_t)(b * CHUNKS + c) * 256 + j) * 8;
    f32x4 o0 = {Qw, Qx, Qy, Qz};
    f32x4 o1 = {S, hx, hy, hz};
    *(f32x4*)op = o0;
    *(f32x4*)(op + 4) = o1;
}

// ---------------- Scan phase 2: sequential fold of 64 chunk operators per chain ----------------
__global__ __launch_bounds__(64) void k_scan_p2(
    const float* __restrict__ ops, float* __restrict__ hs)
{
    int gid = blockIdx.x * 64 + threadIdx.x;   // 0..4095
    int j = gid & 255, b = gid >> 8;

    float q0[PFB], q1[PFB], q2[PFB], q3[PFB], sc[PFB], o0[PFB], o1[PFB], o2[PFB];
    #pragma unroll
    for (int p = 0; p < PFB; ++p) {
        const float* op = ops + ((size_t)(b * CHUNKS + p) * 256 + j) * 8;
        f32x4 a = *(const f32x4*)op, bb = *(const f32x4*)(op + 4);
        q0[p] = a[0]; q1[p] = a[1]; q2[p] = a[2]; q3[p] = a[3];
        sc[p] = bb[0]; o0[p] = bb[1]; o1[p] = bb[2]; o2[p] = bb[3];
    }
    float hx = 0.f, hy = 0.f, hz = 0.f;
    for (int c0 = 0; c0 < CHUNKS; c0 += PFB) {
        #pragma unroll
        for (int p = 0; p < PFB; ++p) {
            int c = c0 + p;
            float* h = hs + ((size_t)(b * CHUNKS + c) * 256 + j) * 3;
            h[0] = hx; h[1] = hy; h[2] = hz;     // h at entry of chunk c
            float w = q0[p], qx = q1[p], qy = q2[p], qz = q3[p];
            float s = sc[p], bx = o0[p], by = o1[p], bz = o2[p];
            int cn = c + PFB;
            if (cn < CHUNKS) {
                const float* op = ops + ((size_t)(b * CHUNKS + cn) * 256 + j) * 8;
                f32x4 a = *(const f32x4*)op, bb = *(const f32x4*)(op + 4);
                q0[p] = a[0]; q1[p] = a[1]; q2[p] = a[2]; q3[p] = a[3];
                sc[p] = bb[0]; o0[p] = bb[1]; o1[p] = bb[2]; o2[p] = bb[3];
            }
            float tx = 2.f * (qy * hz - qz * hy);
            float ty = 2.f * (qz * hx - qx * hz);
            float tz = 2.f * (qx * hy - qy * hx);
            float rx = hx + w * tx + (qy * tz - qz * ty);
            float ry = hy + w * ty + (qz * tx - qx * tz);
            float rz = hz + w * tz + (qx * ty - qy * tx);
            hx = fmaf(s, rx, bx);
            hy = fmaf(s, ry, by);
            hz = fmaf(s, rz, bz);
        }
    }
}

// ---------------- Scan phase 3: chunk scan from h_start + fused per-step LayerNorm + residual ----
__global__ __launch_bounds__(256) void k_scan_p3(
    const u32x2* __restrict__ bivq, const u32x2* __restrict__ injq,
    const float* __restrict__ decay, const float* __restrict__ hs,
    const float* __restrict__ x, const float* __restrict__ gamma,
    const float* __restrict__ beta, float* __restrict__ out)
{
    int blk = blockIdx.x;
    int c = blk & (CHUNKS - 1);
    int b = blk >> 6;
    int j = threadIdx.x;
    size_t rowbase = ((size_t)b * SEQ + (size_t)c * CLEN) * D_MODEL + (size_t)j * 3;
    size_t qrow    = ((size_t)b * SEQ + (size_t)c * CLEN) >> 2;
    const u32x2* bv = bivq + qrow * D_MODEL + 3 * j;
    const u32x2* ij = injq + qrow * D_MODEL + 3 * j;
    const float* xr = x   + rowbase;
    float*       po = out + rowbase;
    const float* dk = decay + (size_t)b * SEQ + c * CLEN;
    const float* h0 = hs + ((size_t)(b * CHUNKS + c) * 256 + j) * 3;
    float hx = h0[0], hy = h0[1], hz = h0[2];
    float Qw = 1.f, Qx = 0.f, Qy = 0.f, Qz = 0.f, S = 1.f;   // unused outputs (kept for macro)

    float g0 = gamma[j * 3], g1 = gamma[j * 3 + 1], g2 = gamma[j * 3 + 2];
    float e0 = beta[j * 3],  e1 = beta[j * 3 + 1],  e2 = beta[j * 3 + 2];

    __shared__ float sb[8];
    __shared__ float mv[2];
    int wid = j >> 6, lane = j & 63;

    u32x2 Ab0, Ab1, Ab2, Ai0, Ai1, Ai2; f32x4 Ad;
    float Ax0, Ax1, Ax2, Ax3, Ax4, Ax5, Ax6, Ax7, Ax8, Ax9, Ax10, Ax11;
    u32x2 Bb0, Bb1, Bb2, Bi0, Bi1, Bi2; f32x4 Bd;
    float Bx0, Bx1, Bx2, Bx3, Bx4, Bx5, Bx6, Bx7, Bx8, Bx9, Bx10, Bx11;

    #define LOADQ3(P, q)                                                  \
        P##b0 = bv[(size_t)(q) * D_MODEL + 0];                            \
        P##b1 = bv[(size_t)(q) * D_MODEL + 1];                            \
        P##b2 = bv[(size_t)(q) * D_MODEL + 2];                            \
        P##i0 = ij[(size_t)(q) * D_MODEL + 0];                            \
        P##i1 = ij[(size_t)(q) * D_MODEL + 1];                            \
        P##i2 = ij[(size_t)(q) * D_MODEL + 2];                            \
        P##d  = *(const f32x4*)(dk + (q) * 4);                            \
        P##x0  = xr[((size_t)(q) * 4 + 0) * D_MODEL + 0];                 \
        P##x1  = xr[((size_t)(q) * 4 + 0) * D_MODEL + 1];                 \
        P##x2  = xr[((size_t)(q) * 4 + 0) * D_MODEL + 2];                 \
        P##x3  = xr[((size_t)(q) * 4 + 1) * D_MODEL + 0];                 \
        P##x4  = xr[((size_t)(q) * 4 + 1) * D_MODEL + 1];                 \
        P##x5  = xr[((size_t)(q) * 4 + 1) * D_MODEL + 2];                 \
        P##x6  = xr[((size_t)(q) * 4 + 2) * D_MODEL + 0];                 \
        P##x7  = xr[((size_t)(q) * 4 + 2) * D_MODEL + 1];                 \
        P##x8  = xr[((size_t)(q) * 4 + 2) * D_MODEL + 2];                 \
        P##x9  = xr[((size_t)(q) * 4 + 3) * D_MODEL + 0];                 \
        P##x10 = xr[((size_t)(q) * 4 + 3) * D_MODEL + 1];                 \
        P##x11 = xr[((size_t)(q) * 4 + 3) * D_MODEL + 2];

    #define STEP3(P, k, T)                                                \
    {   float bx = bfx(P##b0, k), by = bfx(P##b1, k), bz = bfx(P##b2, k); \
        float ix = bfx(P##i0, k), iy = bfx(P##i1, k), iz = bfx(P##i2, k); \
        float d = P##d[k];                                                \
        QSTEP_CORE(bx, by, bz, ix, iy, iz, d)                             \
        float sp = hx + hy + hz;                                          \
        float qp = hx * hx + hy * hy + hz * hz;                           \
        _Pragma("unroll")                                                 \
        for (int off = 32; off; off >>= 1) {                              \
            sp += __shfl_down(sp, off);                                   \
            qp += __shfl_down(qp, off);                                   \
        }                                                                 \
        if (lane == 0) { sb[wid] = sp; sb[wid + 4] = qp; }                \
        __syncthreads();                                                  \
        if (j == 0) {                                                     \
            float Ssum = sb[0] + sb[1] + sb[2] + sb[3];                   \
            float Qsum = sb[4] + sb[5] + sb[6] + sb[7];                   \
            float mean = Ssum * (1.f / 768.f);                            \
            float var  = Qsum * (1.f / 768.f) - mean * mean;              \
            mv[0] = mean; mv[1] = rsqrtf(var + LN_EPS);                   \
        }                                                                 \
        __syncthreads();                                                  \
        float mean = mv[0], rstd = mv[1];                                 \
        float* o2 = po + (size_t)(T) * D_MODEL;                           \
        o2[0] = (hx - mean) * rstd * g0 + e0 + P##x##0j(k, 0);            \
        o2[1] = (hy - mean) * rstd * g1 + e1 + P##x##0j(k, 1);            \
        o2[2] = (hz - mean) * rstd * g2 + e2 + P##x##0j(k, 2);            \
    }

    // helper to name Ax{3k+m} — macro token paste can't compute, so expand per k:
    #define PROC43(P, QBASE)                                              \
    {   { float xa = P##x0,  xbv = P##x1,  xc = P##x2;                    \
          STEP3X(P, 0, (QBASE) * 4 + 0, xa, xbv, xc) }                    \
        { float xa = P##x3,  xbv = P##x4,  xc = P##x5;                    \
          STEP3X(P, 1, (QBASE) * 4 + 1, xa, xbv, xc) }                    \
        { float xa = P##x6,  xbv = P##x7,  xc = P##x8;                    \
          STEP3X(P, 2, (QBASE) * 4 + 2, xa, xbv, xc) }                    \
        { float xa = P##x9,  xbv = P##x10, xc = P##x11;                   \
          STEP3X(P, 3, (QBASE) * 4 + 3, xa, xbv, xc) }                    \
    }

    #define STEP3X(P, k, T, XA, XB, XC)                                   \
    {   float bx = bfx(P##b0, k), by = bfx(P##b1, k), bz = bfx(P##b2, k); \
        float ix = bfx(P##i0, k), iy = bfx(P##i1, k), iz = bfx(P##i2, k); \
        float d = P##d[k];                                                \
        QSTEP_CORE(bx, by, bz, ix, iy, iz, d)                             \
        float sp = hx + hy + hz;                                          \
        float qp = hx * hx + hy * hy + hz * hz;                           \
        _Pragma("unroll")                                                 \
        for (int off = 32; off; off >>= 1) {                              \
            sp += __shfl_down(sp, off);                                   \
            qp += __shfl_down(qp, off);                                   \
        }                                                                 \
        if (lane == 0) { sb[wid] = sp; sb[wid + 4] = qp; }                \
        __syncthreads();                                                  \
        if (j == 0) {                                                     \
            float Ssum = sb[0] + sb[1] + sb[2] + sb[3];                   \
            float Qsum = sb[4] + sb[5] + sb[6] + sb[7];                   \
            float mean = Ssum * (1.f / 768.f);                            \
            float var  = Qsum * (1.f / 768.f) - mean * mean;              \
            mv[0] = mean; mv[1] = rsqrtf(var + LN_EPS);                   \
        }                                                                 \
        __syncthreads();                                                  \
        float mean = mv[0], rstd = mv[1];                                 \
        float* o2 = po + (size_t)(T) * D_MODEL;                           \
        o2[0] = (hx - mean) * rstd * g0 + e0 + (XA);                      \
        o2[1] = (hy - mean) * rstd * g1 + e1 + (XB);                      \
        o2[2] = (hz - mean) * rstd * g2 + e2 + (XC);                      \
    }

    LOADQ3(A, 0)
    LOADQ3(B, 1)
    #pragma unroll
    for (int q0 = 0; q0 < CLEN / 4; q0 += 2) {
        PROC43(A, q0)
        if (q0 + 2 < CLEN / 4) { LOADQ3(A, q0 + 2) }
        PROC43(B, q0 + 1)
        if (q0 + 3 < CLEN / 4) { LOADQ3(B, q0 + 3) }
    }
    (void)Qw; (void)Qx; (void)Qy; (void)Qz; (void)S;
}

extern "C" void kernel_launch(void* const* d_in, const int* in_sizes, int n_in,
                              void* d_out, int out_size, void* d_ws, size_t ws_size,
                              hipStream_t stream) {
    const float* x     = (const float*)d_in[0];
    const float* W_biv = (const float*)d_in[1];
    const float* b_biv = (const float*)d_in[2];
    const float* W_dec = (const float*)d_in[3];
    const float* b_dec = (const float*)d_in[4];
    const float* W_in  = (const float*)d_in[5];
    const float* b_in  = (const float*)d_in[6];
    const float* gamma = (const float*)d_in[7];
    const float* beta  = (const float*)d_in[8];
    float* out = (float*)d_out;

    // workspace layout (153.5 MB)
    char* ws = (char*)d_ws;
    unsigned short* xb    = (unsigned short*)(ws);               // 50,331,648 B (dead after GEMM)
    unsigned short* Wcat  = (unsigned short*)(ws + 50331648);    //  2,359,296 B (1536x768 bf16)
    float*          decay = (float*)         (ws + 52690944);    //    131,072 B
    u32x2*          bivq  = (u32x2*)         (ws + 52822016);    // 50,331,648 B (quad-packed bf16)
    u32x2*          injq  = (u32x2*)         (ws + 103153664);   // 50,331,648 B (quad-packed bf16)
    // scan scratch reuses the xb region (dead after GEMM)
    float*          ops   = (float*)(ws);                        //  8,388,608 B
    float*          hs    = (float*)(ws + 8388608);              //  3,145,728 B

    (void)in_sizes; (void)n_in; (void)out_size; (void)ws_size;

    k_conv_decay<<<M_ROWS, 256, 0, stream>>>(x, W_dec, b_dec, xb, decay);
    k_conv_w    <<<1152,   256, 0, stream>>>(W_biv, W_in, Wcat);
    k_gemm_fused<<<NBX * (M_ROWS / BM), 256, 0, stream>>>(xb, Wcat, b_biv, b_in, bivq, injq);
    k_scan_p1   <<<1024, 256, 0, stream>>>(bivq, injq, decay, ops);
    k_scan_p2   <<<64,   64,  0, stream>>>(ops, hs);
    k_scan_p3   <<<1024, 256, 0, stream>>>(bivq, injq, decay, hs, x, gamma, beta, out);
}

// Round 7
// 220.149 us; speedup vs baseline: 1.2648x; 1.0561x over previous
//
#include <hip/hip_runtime.h>
#include <stdint.h>

#define D_MODEL 768
#define BATCH   16
#define SEQ     2048
#define M_ROWS  (BATCH * SEQ)   // 32768
#define LN_EPS  1e-5f

#define CHUNKS  64
#define CLEN    (SEQ / CHUNKS)  // 32
#define PFB     8               // prefetch depth, phase 2

typedef __attribute__((ext_vector_type(4))) float        f32x4;
typedef __attribute__((ext_vector_type(8))) __bf16       bf16x8;
typedef __attribute__((ext_vector_type(2))) unsigned int u32x2;

__device__ __forceinline__ unsigned short f2bf(float f) {
    union { float f; uint32_t u; } v; v.f = f;
    uint32_t u = v.u;
    uint32_t r = (u + 0x7FFFu + ((u >> 16) & 1u)) >> 16;   // RNE
    return (unsigned short)r;
}
__device__ __forceinline__ float bf2f(unsigned short u) {
    union { uint32_t u; float f; } v; v.u = (uint32_t)u << 16; return v.f;
}
// extract element k (0..3) of a packed quad (4 bf16 in 8B)
__device__ __forceinline__ float bfx(u32x2 v, int k) {
    unsigned int w = (k & 2) ? v[1] : v[0];
    return bf2f((unsigned short)(w >> ((k & 1) * 16)));
}

__device__ __forceinline__ void gload_lds16(const void* g, void* l) {
    __builtin_amdgcn_global_load_lds(
        (const __attribute__((address_space(1))) unsigned int*)g,
        (__attribute__((address_space(3))) unsigned int*)l,
        16, 0, 0);
}

// ---------------- Kernel 1: convert x -> bf16, fused decay GEMV ----------------
__global__ __launch_bounds__(256) void k_conv_decay(
    const float* __restrict__ x, const float* __restrict__ Wd,
    const float* __restrict__ bd, unsigned short* __restrict__ xb,
    float* __restrict__ decay)
{
    int row = blockIdx.x;
    int i   = threadIdx.x;
    const float* xr = x + (size_t)row * D_MODEL;
    float v0 = xr[i], v1 = xr[i + 256], v2 = xr[i + 512];
    unsigned short* xbr = xb + (size_t)row * D_MODEL;
    xbr[i] = f2bf(v0); xbr[i + 256] = f2bf(v1); xbr[i + 512] = f2bf(v2);

    float part = v0 * Wd[i] + v1 * Wd[i + 256] + v2 * Wd[i + 512];
    #pragma unroll
    for (int off = 32; off; off >>= 1) part += __shfl_down(part, off);
    __shared__ float wsum[4];
    int wid = i >> 6, lane = i & 63;
    if (lane == 0) wsum[wid] = part;
    __syncthreads();
    if (i == 0) {
        float s = wsum[0] + wsum[1] + wsum[2] + wsum[3] + bd[0];
        decay[row] = 1.f / (1.f + __expf(-s));
    }
}

// ---------------- Kernel 2: convert both weight matrices to bf16 (contiguous dest) ----------------
__global__ __launch_bounds__(256) void k_conv_w(
    const float* __restrict__ Wb, const float* __restrict__ Wi,
    unsigned short* __restrict__ Wdst)   // (1536,768): rows 0..767 = W_biv, 768..1535 = W_in
{
    const int NW = D_MODEL * D_MODEL;          // 589824
    int g = blockIdx.x * 256 + threadIdx.x;
    int base = g * 4;
    unsigned short* dst = Wdst + base;
    const float* src;
    if (base < NW) { src = Wb + base; }
    else           { src = Wi + (base - NW); }
    float4 v = *(const float4*)src;
    ushort4 o;
    o.x = f2bf(v.x); o.y = f2bf(v.y); o.z = f2bf(v.z); o.w = f2bf(v.w);
    *(ushort4*)dst = o;
}

// ---------------- Kernel 3: 256x256 deep-pipelined bf16 MFMA GEMM ----------------
// C(M,1536) = A(M,768) * W(1536,768)^T + bias, quad-packed bf16 output.
// 8 waves (2Mx4N), BK=64 split into 2 column-halves stored as contiguous LDS blocks.
// Counted vmcnt: stage half H+3 while consuming H; certify H+1 with vmcnt(8) each phase.
#define GBM 256
#define GBN 256
#define GNBX 6    // 1536/256
#define GNBY 128  // 32768/256
#define NT   12   // 768/64 K-tiles

__global__ __launch_bounds__(512, 2) void k_gemm_fused(
    const unsigned short* __restrict__ A,    // (M,768) bf16 row-major
    const unsigned short* __restrict__ Bw,   // (1536,768) bf16 row-major
    const float* __restrict__ bias_biv, const float* __restrict__ bias_in,
    u32x2* __restrict__ bivq, u32x2* __restrict__ injq)
{
    extern __shared__ unsigned short LDSBUF[];
    unsigned short* LA = LDSBUF;            // [2 buf][2 half][256 row][32 col] = 65536 B
    unsigned short* LB = LDSBUF + 32768;    // same, 65536 B

    // XCD-chunked swizzle: 768 blocks, 96 per XCD (16 M-panels x 6 N) -> A-panel L2 reuse
    int id  = blockIdx.x;
    int swz = (id & 7) * 96 + (id >> 3);
    int bxc = swz % GNBX, byr = swz / GNBX;
    int m0 = byr * GBM, n0 = bxc * GBN;

    int tid  = threadIdx.x;
    int wid  = tid >> 6, lane = tid & 63;
    int wm = wid >> 2, wn = wid & 3;        // 2x4 wave grid; wave tile 128x64
    int rl = lane & 15, kq = lane >> 4;
    int sl = kq ^ ((rl >> 1) & 3);          // read-side 16B-slot XOR swizzle
    int aoff = (wm * 128 + rl) * 32 + sl * 8;   // ushort offset within a half-block
    int boff = (wn * 64  + rl) * 32 + sl * 8;

    f32x4 acc[8][4] = {};

    // stage one 32-K column-half of both A and B tiles (4 gloads/thread)
    #define STAGE_HALF(DBUF, KT, HH) do {                                        \
        _Pragma("unroll")                                                        \
        for (int p = 0; p < 2; ++p) {                                            \
            int idx = p * 512 + tid;                                             \
            int row = idx >> 2;                                                  \
            int ss  = ((idx & 3) ^ ((idx >> 3) & 3)) * 8;  /* pre-swizzled src */\
            gload_lds16(A  + (size_t)(m0 + row) * D_MODEL + (KT) * 64 + (HH) * 32 + ss, \
                        LA + (DBUF) * 16384 + (HH) * 8192 + idx * 8);            \
            gload_lds16(Bw + (size_t)(n0 + row) * D_MODEL + (KT) * 64 + (HH) * 32 + ss, \
                        LB + (DBUF) * 16384 + (HH) * 8192 + idx * 8);            \
        }                                                                        \
    } while (0)

    #define PHASE(D, H, DOSTAGE, SBUF, SKT, SHH, WAITSTR) do {                   \
        bf16x8 af[8], bfv[4];                                                    \
        const unsigned short* pa = LA + (D) * 16384 + (H) * 8192 + aoff;         \
        const unsigned short* pb = LB + (D) * 16384 + (H) * 8192 + boff;         \
        _Pragma("unroll")                                                        \
        for (int i = 0; i < 8; ++i) af[i]  = *(const bf16x8*)(pa + i * 512);     \
        _Pragma("unroll")                                                        \
        for (int j = 0; j < 4; ++j) bfv[j] = *(const bf16x8*)(pb + j * 512);     \
        if (DOSTAGE) STAGE_HALF(SBUF, SKT, SHH);                                 \
        asm volatile(WAITSTR ::: "memory");                                      \
        asm volatile("s_barrier" ::: "memory");                                  \
        asm volatile("s_waitcnt lgkmcnt(0)" ::: "memory");                       \
        __builtin_amdgcn_sched_barrier(0);                                       \
        __builtin_amdgcn_s_setprio(1);                                           \
        _Pragma("unroll")                                                        \
        for (int i = 0; i < 8; ++i)                                              \
            _Pragma("unroll")                                                    \
            for (int j = 0; j < 4; ++j)                                          \
                acc[i][j] = __builtin_amdgcn_mfma_f32_16x16x32_bf16(             \
                    af[i], bfv[j], acc[i][j], 0, 0, 0);                          \
        __builtin_amdgcn_s_setprio(0);                                           \
        asm volatile("s_barrier" ::: "memory");                                  \
    } while (0)

    // prologue: halves (0,0),(0,1),(1,0) in flight; certify half 0
    STAGE_HALF(0, 0, 0);
    STAGE_HALF(0, 0, 1);
    STAGE_HALF(1, 1, 0);
    asm volatile("s_waitcnt vmcnt(8)" ::: "memory");
    asm volatile("s_barrier" ::: "memory");

    for (int t = 0; t < 10; ++t) {
        int cur = t & 1;
        PHASE(cur, 0, true, cur ^ 1, t + 1, 1, "s_waitcnt vmcnt(8)");
        PHASE(cur, 1, true, cur,     t + 2, 0, "s_waitcnt vmcnt(8)");
    }
    PHASE(0, 0, true,  1, 11, 1, "s_waitcnt vmcnt(8)");   // t=10 ph0: stage (11,1)
    PHASE(0, 1, false, 0, 0,  0, "s_waitcnt vmcnt(4)");   // t=10 ph1
    PHASE(1, 0, false, 0, 0,  0, "s_waitcnt vmcnt(0)");   // t=11 ph0
    PHASE(1, 1, false, 0, 0,  0, "");                     // t=11 ph1

    #undef PHASE
    #undef STAGE_HALF

    // epilogue: quad-packed bf16 stores (rows quad-aligned), 32 x 8B per lane
    u32x2* Cq; const float* bias; int nloc;
    if (n0 < D_MODEL) { Cq = bivq; bias = bias_biv; nloc = n0; }
    else              { Cq = injq; bias = bias_in;  nloc = n0 - D_MODEL; }
    int cl = lane & 15;
    int qbase = (m0 >> 2) + wm * 32 + (lane >> 4);
    #pragma unroll
    for (int j = 0; j < 4; ++j) {
        int col = nloc + wn * 64 + j * 16 + cl;
        float bs = bias[col];
        #pragma unroll
        for (int i = 0; i < 8; ++i) {
            f32x4 a = acc[i][j];
            unsigned int lo = (unsigned int)f2bf(a[0] + bs) | ((unsigned int)f2bf(a[1] + bs) << 16);
            unsigned int hi = (unsigned int)f2bf(a[2] + bs) | ((unsigned int)f2bf(a[3] + bs) << 16);
            u32x2 pk = {lo, hi};
            Cq[(size_t)(qbase + i * 4) * D_MODEL + col] = pk;
        }
    }
}

// ---------------- Scan step macros ----------------
#define QSTEP_CORE(BX,BY,BZ, IX,IY,IZ, DD)                              \
    {   float n2   = (BX)*(BX) + (BY)*(BY) + (BZ)*(BZ);                 \
        float nrm  = fmaxf(__builtin_sqrtf(n2), 1e-8f);                 \
        float half = 0.5f * nrm;                                        \
        float w = __cosf(half);                                         \
        float s = __sinf(half) / nrm;                                   \
        float qx = s * (BZ), qy = -s * (BY), qz = s * (BX);             \
        float tx = 2.f * (qy * hz - qz * hy);                           \
        float ty = 2.f * (qz * hx - qx * hz);                           \
        float tz = 2.f * (qx * hy - qy * hx);                           \
        float rx = hx + w * tx + (qy * tz - qz * ty);                   \
        float ry = hy + w * ty + (qz * tx - qx * tz);                   \
        float rz = hz + w * tz + (qx * ty - qy * tx);                   \
        hx = fmaf((DD), rx, (IX));                                      \
        hy = fmaf((DD), ry, (IY));                                      \
        hz = fmaf((DD), rz, (IZ));                                      \
        float nQw = w * Qw - qx * Qx - qy * Qy - qz * Qz;               \
        float nQx = w * Qx + Qw * qx + (qy * Qz - qz * Qy);             \
        float nQy = w * Qy + Qw * qy + (qz * Qx - qx * Qz);             \
        float nQz = w * Qz + Qw * qz + (qx * Qy - qy * Qx);             \
        Qw = nQw; Qx = nQx; Qy = nQy; Qz = nQz;                         \
        S *= (DD);                                                      \
    }

// ---------------- Scan phase 1: per-(chain,chunk) operator compose (quad-packed reads) ----
__global__ __launch_bounds__(256) void k_scan_p1(
    const u32x2* __restrict__ bivq, const u32x2* __restrict__ injq,
    const float* __restrict__ decay,
    float* __restrict__ ops)          // per (b,c,j): {Qw,Qx,Qy,Qz,S,bx,by,bz}
{
    int j = threadIdx.x;
    int c = blockIdx.x & (CHUNKS - 1);
    int b = blockIdx.x >> 6;
    size_t qrow = ((size_t)b * SEQ + (size_t)c * CLEN) >> 2;
    const u32x2* bv = bivq + qrow * D_MODEL + 3 * j;
    const u32x2* ij = injq + qrow * D_MODEL + 3 * j;
    const float* dk = decay + (size_t)b * SEQ + c * CLEN;

    u32x2 Ab0, Ab1, Ab2, Ai0, Ai1, Ai2; f32x4 Ad;
    u32x2 Bb0, Bb1, Bb2, Bi0, Bi1, Bi2; f32x4 Bd;

    #define LOADQ1(P, q)                                                  \
        P##b0 = bv[(size_t)(q) * D_MODEL + 0];                            \
        P##b1 = bv[(size_t)(q) * D_MODEL + 1];                            \
        P##b2 = bv[(size_t)(q) * D_MODEL + 2];                            \
        P##i0 = ij[(size_t)(q) * D_MODEL + 0];                            \
        P##i1 = ij[(size_t)(q) * D_MODEL + 1];                            \
        P##i2 = ij[(size_t)(q) * D_MODEL + 2];                            \
        P##d  = *(const f32x4*)(dk + (q) * 4);

    #define PROC41(P)                                                     \
        _Pragma("unroll")                                                 \
        for (int k = 0; k < 4; ++k) {                                     \
            float bx = bfx(P##b0, k), by = bfx(P##b1, k), bz = bfx(P##b2, k); \
            float ix = bfx(P##i0, k), iy = bfx(P##i1, k), iz = bfx(P##i2, k); \
            float d = P##d[k];                                            \
            QSTEP_CORE(bx, by, bz, ix, iy, iz, d)                         \
        }

    float hx = 0.f, hy = 0.f, hz = 0.f;
    float Qw = 1.f, Qx = 0.f, Qy = 0.f, Qz = 0.f, S = 1.f;

    LOADQ1(A, 0)
    LOADQ1(B, 1)
    #pragma unroll
    for (int q0 = 0; q0 < CLEN / 4; q0 += 2) {
        PROC41(A)
        if (q0 + 2 < CLEN / 4) { LOADQ1(A, q0 + 2) }
        PROC41(B)
        if (q0 + 3 < CLEN / 4) { LOADQ1(B, q0 + 3) }
    }
    #undef LOADQ1
    #undef PROC41

    float* op = ops + ((size_t)(b * CHUNKS + c) * 256 + j) * 8;
    f32x4 o0 = {Qw, Qx, Qy, Qz};
    f32x4 o1 = {S, hx, hy, hz};
    *(f32x4*)op = o0;
    *(f32x4*)(op + 4) = o1;
}

// ---------------- Scan phase 2: sequential fold of 64 chunk operators per chain ----------------
__global__ __launch_bounds__(64) void k_scan_p2(
    const float* __restrict__ ops, float* __restrict__ hs)
{
    int gid = blockIdx.x * 64 + threadIdx.x;   // 0..4095
    int j = gid & 255, b = gid >> 8;

    float q0[PFB], q1[PFB], q2[PFB], q3[PFB], sc[PFB], o0[PFB], o1[PFB], o2[PFB];
    #pragma unroll
    for (int p = 0; p < PFB; ++p) {
        const float* op = ops + ((size_t)(b * CHUNKS + p) * 256 + j) * 8;
        f32x4 a = *(const f32x4*)op, bb = *(const f32x4*)(op + 4);
        q0[p] = a[0]; q1[p] = a[1]; q2[p] = a[2]; q3[p] = a[3];
        sc[p] = bb[0]; o0[p] = bb[1]; o1[p] = bb[2]; o2[p] = bb[3];
    }
    float hx = 0.f, hy = 0.f, hz = 0.f;
    for (int c0 = 0; c0 < CHUNKS; c0 += PFB) {
        #pragma unroll
        for (int p = 0; p < PFB; ++p) {
            int c = c0 + p;
            float* h = hs + ((size_t)(b * CHUNKS + c) * 256 + j) * 3;
            h[0] = hx; h[1] = hy; h[2] = hz;     // h at entry of chunk c
            float w = q0[p], qx = q1[p], qy = q2[p], qz = q3[p];
            float s = sc[p], bx = o0[p], by = o1[p], bz = o2[p];
            int cn = c + PFB;
            if (cn < CHUNKS) {
                const float* op = ops + ((size_t)(b * CHUNKS + cn) * 256 + j) * 8;
                f32x4 a = *(const f32x4*)op, bb = *(const f32x4*)(op + 4);
                q0[p] = a[0]; q1[p] = a[1]; q2[p] = a[2]; q3[p] = a[3];
                sc[p] = bb[0]; o0[p] = bb[1]; o1[p] = bb[2]; o2[p] = bb[3];
            }
            float tx = 2.f * (qy * hz - qz * hy);
            float ty = 2.f * (qz * hx - qx * hz);
            float tz = 2.f * (qx * hy - qy * hx);
            float rx = hx + w * tx + (qy * tz - qz * ty);
            float ry = hy + w * ty + (qz * tx - qx * tz);
            float rz = hz + w * tz + (qx * ty - qy * tx);
            hx = fmaf(s, rx, bx);
            hy = fmaf(s, ry, by);
            hz = fmaf(s, rz, bz);
        }
    }
}

// ---------------- Scan phase 3: chunk scan from h_start + fused per-step LayerNorm + residual ----
__global__ __launch_bounds__(256) void k_scan_p3(
    const u32x2* __restrict__ bivq, const u32x2* __restrict__ injq,
    const float* __restrict__ decay, const float* __restrict__ hs,
    const float* __restrict__ x, const float* __restrict__ gamma,
    const float* __restrict__ beta, float* __restrict__ out)
{
    int blk = blockIdx.x;
    int c = blk & (CHUNKS - 1);
    int b = blk >> 6;
    int j = threadIdx.x;
    size_t rowbase = ((size_t)b * SEQ + (size_t)c * CLEN) * D_MODEL + (size_t)j * 3;
    size_t qrow    = ((size_t)b * SEQ + (size_t)c * CLEN) >> 2;
    const u32x2* bv = bivq + qrow * D_MODEL + 3 * j;
    const u32x2* ij = injq + qrow * D_MODEL + 3 * j;
    const float* xr = x   + rowbase;
    float*       po = out + rowbase;
    const float* dk = decay + (size_t)b * SEQ + c * CLEN;
    const float* h0 = hs + ((size_t)(b * CHUNKS + c) * 256 + j) * 3;
    float hx = h0[0], hy = h0[1], hz = h0[2];
    float Qw = 1.f, Qx = 0.f, Qy = 0.f, Qz = 0.f, S = 1.f;   // unused outputs (kept for macro)

    float g0 = gamma[j * 3], g1 = gamma[j * 3 + 1], g2 = gamma[j * 3 + 2];
    float e0 = beta[j * 3],  e1 = beta[j * 3 + 1],  e2 = beta[j * 3 + 2];

    __shared__ float sb[8];
    __shared__ float mv[2];
    int wid = j >> 6, lane = j & 63;

    u32x2 Ab0, Ab1, Ab2, Ai0, Ai1, Ai2; f32x4 Ad;
    float Ax0, Ax1, Ax2, Ax3, Ax4, Ax5, Ax6, Ax7, Ax8, Ax9, Ax10, Ax11;
    u32x2 Bb0, Bb1, Bb2, Bi0, Bi1, Bi2; f32x4 Bd;
    float Bx0, Bx1, Bx2, Bx3, Bx4, Bx5, Bx6, Bx7, Bx8, Bx9, Bx10, Bx11;

    #define LOADQ3(P, q)                                                  \
        P##b0 = bv[(size_t)(q) * D_MODEL + 0];                            \
        P##b1 = bv[(size_t)(q) * D_MODEL + 1];                            \
        P##b2 = bv[(size_t)(q) * D_MODEL + 2];                            \
        P##i0 = ij[(size_t)(q) * D_MODEL + 0];                            \
        P##i1 = ij[(size_t)(q) * D_MODEL + 1];                            \
        P##i2 = ij[(size_t)(q) * D_MODEL + 2];                            \
        P##d  = *(const f32x4*)(dk + (q) * 4);                            \
        P##x0  = xr[((size_t)(q) * 4 + 0) * D_MODEL + 0];                 \
        P##x1  = xr[((size_t)(q) * 4 + 0) * D_MODEL + 1];                 \
        P##x2  = xr[((size_t)(q) * 4 + 0) * D_MODEL + 2];                 \
        P##x3  = xr[((size_t)(q) * 4 + 1) * D_MODEL + 0];                 \
        P##x4  = xr[((size_t)(q) * 4 + 1) * D_MODEL + 1];                 \
        P##x5  = xr[((size_t)(q) * 4 + 1) * D_MODEL + 2];                 \
        P##x6  = xr[((size_t)(q) * 4 + 2) * D_MODEL + 0];                 \
        P##x7  = xr[((size_t)(q) * 4 + 2) * D_MODEL + 1];                 \
        P##x8  = xr[((size_t)(q) * 4 + 2) * D_MODEL + 2];                 \
        P##x9  = xr[((size_t)(q) * 4 + 3) * D_MODEL + 0];                 \
        P##x10 = xr[((size_t)(q) * 4 + 3) * D_MODEL + 1];                 \
        P##x11 = xr[((size_t)(q) * 4 + 3) * D_MODEL + 2];

    #define PROC43(P, QBASE)                                              \
    {   { float xa = P##x0,  xbv = P##x1,  xc = P##x2;                    \
          STEP3X(P, 0, (QBASE) * 4 + 0, xa, xbv, xc) }                    \
        { float xa = P##x3,  xbv = P##x4,  xc = P##x5;                    \
          STEP3X(P, 1, (QBASE) * 4 + 1, xa, xbv, xc) }                    \
        { float xa = P##x6,  xbv = P##x7,  xc = P##x8;                    \
          STEP3X(P, 2, (QBASE) * 4 + 2, xa, xbv, xc) }                    \
        { float xa = P##x9,  xbv = P##x10, xc = P##x11;                   \
          STEP3X(P, 3, (QBASE) * 4 + 3, xa, xbv, xc) }                    \
    }

    #define STEP3X(P, k, T, XA, XB, XC)                                   \
    {   float bx = bfx(P##b0, k), by = bfx(P##b1, k), bz = bfx(P##b2, k); \
        float ix = bfx(P##i0, k), iy = bfx(P##i1, k), iz = bfx(P##i2, k); \
        float d = P##d[k];                                                \
        QSTEP_CORE(bx, by, bz, ix, iy, iz, d)                             \
        float sp = hx + hy + hz;                                          \
        float qp = hx * hx + hy * hy + hz * hz;                           \
        _Pragma("unroll")                                                 \
        for (int off = 32; off; off >>= 1) {                              \
            sp += __shfl_down(sp, off);                                   \
            qp += __shfl_down(qp, off);                                   \
        }                                                                 \
        if (lane == 0) { sb[wid] = sp; sb[wid + 4] = qp; }                \
        __syncthreads();                                                  \
        if (j == 0) {                                                     \
            float Ssum = sb[0] + sb[1] + sb[2] + sb[3];                   \
            float Qsum = sb[4] + sb[5] + sb[6] + sb[7];                   \
            float mean = Ssum * (1.f / 768.f);                            \
            float var  = Qsum * (1.f / 768.f) - mean * mean;              \
            mv[0] = mean; mv[1] = rsqrtf(var + LN_EPS);                   \
        }                                                                 \
        __syncthreads();                                                  \
        float mean = mv[0], rstd = mv[1];                                 \
        float* o2 = po + (size_t)(T) * D_MODEL;                           \
        o2[0] = (hx - mean) * rstd * g0 + e0 + (XA);                      \
        o2[1] = (hy - mean) * rstd * g1 + e1 + (XB);                      \
        o2[2] = (hz - mean) * rstd * g2 + e2 + (XC);                      \
    }

    LOADQ3(A, 0)
    LOADQ3(B, 1)
    #pragma unroll
    for (int q0 = 0; q0 < CLEN / 4; q0 += 2) {
        PROC43(A, q0)
        if (q0 + 2 < CLEN / 4) { LOADQ3(A, q0 + 2) }
        PROC43(B, q0 + 1)
        if (q0 + 3 < CLEN / 4) { LOADQ3(B, q0 + 3) }
    }
    (void)Qw; (void)Qx; (void)Qy; (void)Qz; (void)S;
}

extern "C" void kernel_launch(void* const* d_in, const int* in_sizes, int n_in,
                              void* d_out, int out_size, void* d_ws, size_t ws_size,
                              hipStream_t stream) {
    const float* x     = (const float*)d_in[0];
    const float* W_biv = (const float*)d_in[1];
    const float* b_biv = (const float*)d_in[2];
    const float* W_dec = (const float*)d_in[3];
    const float* b_dec = (const float*)d_in[4];
    const float* W_in  = (const float*)d_in[5];
    const float* b_in  = (const float*)d_in[6];
    const float* gamma = (const float*)d_in[7];
    const float* beta  = (const float*)d_in[8];
    float* out = (float*)d_out;

    // workspace layout (153.5 MB)
    char* ws = (char*)d_ws;
    unsigned short* xb    = (unsigned short*)(ws);               // 50,331,648 B (dead after GEMM)
    unsigned short* Wcat  = (unsigned short*)(ws + 50331648);    //  2,359,296 B (1536x768 bf16)
    float*          decay = (float*)         (ws + 52690944);    //    131,072 B
    u32x2*          bivq  = (u32x2*)         (ws + 52822016);    // 50,331,648 B (quad-packed bf16)
    u32x2*          injq  = (u32x2*)         (ws + 103153664);   // 50,331,648 B (quad-packed bf16)
    // scan scratch reuses the xb region (dead after GEMM)
    float*          ops   = (float*)(ws);                        //  8,388,608 B
    float*          hs    = (float*)(ws + 8388608);              //  3,145,728 B

    (void)in_sizes; (void)n_in; (void)out_size; (void)ws_size;

    // allow 128 KiB dynamic LDS for the GEMM (host-side attribute, graph-capture-safe)
    hipFuncSetAttribute((const void*)k_gemm_fused,
                        hipFuncAttributeMaxDynamicSharedMemorySize, 131072);

    k_conv_decay<<<M_ROWS, 256, 0, stream>>>(x, W_dec, b_dec, xb, decay);
    k_conv_w    <<<1152,   256, 0, stream>>>(W_biv, W_in, Wcat);
    k_gemm_fused<<<GNBX * GNBY, 512, 131072, stream>>>(xb, Wcat, b_biv, b_in, bivq, injq);
    k_scan_p1   <<<1024, 256, 0, stream>>>(bivq, injq, decay, ops);
    k_scan_p2   <<<64,   64,  0, stream>>>(ops, hs);
    k_scan_p3   <<<1024, 256, 0, stream>>>(bivq, injq, decay, hs, x, gamma, beta, out);
}